// Round 5
// baseline (5746.310 us; speedup 1.0000x reference)
//
#include <hip/hip_runtime.h>

#define NL 4000
#define NC 8000
#define EMB 128
#define ROWC0 4096           // clause region start
#define NRP 12288            // padded total rows (192 x 64)
#define NRREAL (ROWC0 + NC)  // 12096 rows with data
#define TSTEPS 30
#define LCHUNK 80
#define NCHUNK 50

typedef __attribute__((ext_vector_type(8))) short bf16x8;
typedef __attribute__((ext_vector_type(4))) float f32x4;

__device__ __forceinline__ short f2bf(float x) {
    union { float f; unsigned u; } v; v.f = x;
    unsigned r = v.u + 0x7fffu + ((v.u >> 16) & 1u);
    return (short)(r >> 16);
}
__device__ __forceinline__ float bf2f(short s) {
    union { unsigned u; float f; } v; v.u = ((unsigned)(unsigned short)s) << 16;
    return v.f;
}
__device__ __forceinline__ float sigf(float x) { return 1.f / (1.f + expf(-x)); }

// ---------------------------------------------------------------------------
// Barrier-free split-bf16 MFMA GEMM. One wave (64 thr) per 64x64 output tile.
// Fragments loaded DIRECTLY from global (L2-resident weights/activations):
// lane l holds A[row0+s*16+(l&15)][kc+(l>>4)*8 ..+7].
// product = Ah*Wh + Ah*Wl + Al*Wh in fp32 acc (~2^-17 rel err).
// OUTM: 0 = fp32 out, 1 = split-bf16 out (+optional relu),
//       3 = permuted-gate LSTM fusion (TWOA: A1=msgs.Wih + A2=H.Whh).
// Rows < ROWC0 use L weight set, else C set.
// ---------------------------------------------------------------------------
template<int KS, int OUTM, bool TWOA, bool RELU, bool PERMB>
__global__ __launch_bounds__(64) void gemm64(
    const short* __restrict__ A1h, const short* __restrict__ A1l,
    const short* __restrict__ A2h, const short* __restrict__ A2l,
    const short* __restrict__ B1hL, const short* __restrict__ B1lL,
    const short* __restrict__ B1hC, const short* __restrict__ B1lC,
    const short* __restrict__ B2hL, const short* __restrict__ B2lL,
    const short* __restrict__ B2hC, const short* __restrict__ B2lC,
    const float* __restrict__ biasL, const float* __restrict__ biasC,
    short* __restrict__ OH, short* __restrict__ OL, float* __restrict__ OF,
    const float* __restrict__ Cold, float* __restrict__ Cnew,
    int Freal, int Fstore)
{
    const int lane = threadIdx.x;
    const int row0 = blockIdx.y * 64;
    const int c0 = blockIdx.x * 64;
    const bool isC = row0 >= ROWC0;
    const int l15 = lane & 15;
    const int kq = (lane >> 4) << 3;

    f32x4 acc[4][4] = {};

#pragma unroll
    for (int ph = 0; ph < (TWOA ? 2 : 1); ++ph) {
        const short* Ah = (TWOA && ph) ? A2h : A1h;
        const short* Al = (TWOA && ph) ? A2l : A1l;
        const short* Bh = (TWOA && ph) ? (isC ? B2hC : B2hL) : (isC ? B1hC : B1hL);
        const short* Bl = (TWOA && ph) ? (isC ? B2lC : B2lL) : (isC ? B1lC : B1lL);
#pragma unroll
        for (int kc = 0; kc < KS; kc += 32) {
            const int k = kc + kq;
            bf16x8 af[4][2], bf[4][2];
#pragma unroll
            for (int s = 0; s < 4; ++s) {
                size_t ai = (size_t)(row0 + s * 16 + l15) * KS + k;
                af[s][0] = *(const bf16x8*)(Ah + ai);
                af[s][1] = *(const bf16x8*)(Al + ai);
                int col = c0 + s * 16 + l15;
                int wr = PERMB ? ((col & 3) * 128 + (col >> 2)) : col;
                size_t bi = (size_t)wr * KS + k;
                bf[s][0] = *(const bf16x8*)(Bh + bi);
                bf[s][1] = *(const bf16x8*)(Bl + bi);
            }
#pragma unroll
            for (int s = 0; s < 4; ++s)
#pragma unroll
                for (int u = 0; u < 4; ++u) {
                    acc[s][u] = __builtin_amdgcn_mfma_f32_16x16x32_bf16(af[s][0], bf[u][0], acc[s][u], 0, 0, 0);
                    acc[s][u] = __builtin_amdgcn_mfma_f32_16x16x32_bf16(af[s][0], bf[u][1], acc[s][u], 0, 0, 0);
                    acc[s][u] = __builtin_amdgcn_mfma_f32_16x16x32_bf16(af[s][1], bf[u][0], acc[s][u], 0, 0, 0);
                }
        }
    }

    if (OUTM != 3) {
        // C/D layout: col = lane&15, row = (lane>>4)*4 + reg (m89-verified)
#pragma unroll
        for (int u = 0; u < 4; ++u) {
            int col = c0 + u * 16 + l15;
            if (col >= Fstore) continue;
            float bv = (col < Freal) ? (isC ? biasC[col] : biasL[col]) : 0.f;
#pragma unroll
            for (int s = 0; s < 4; ++s)
#pragma unroll
                for (int j = 0; j < 4; ++j) {
                    int row = row0 + s * 16 + (lane >> 4) * 4 + j;
                    float v = acc[s][u][j] + bv;
                    if (RELU) v = fmaxf(v, 0.f);
                    size_t oi = (size_t)row * Fstore + col;
                    if (OUTM == 1) {
                        short h = f2bf(v);
                        OH[oi] = h;
                        OL[oi] = f2bf(v - bf2f(h));
                    } else {
                        OF[oi] = v;
                    }
                }
        }
    } else {
        // Fused LSTM epilogue. Permuted gate space: col 4j+g holds gate g of
        // dim j. shfl_xor{1,2,3} gathers the quadruple; lane q=lane&3 owns
        // the cell at reg q. (Gate-permutation verified: R4 absmax 1.46e-3,
        // purely bf16-X rounding scale — no layout-scale error.)
        const int q = lane & 3;
#pragma unroll
        for (int u = 0; u < 4; ++u) {
            int colp = c0 + u * 16 + l15;
            int wr = (colp & 3) * 128 + (colp >> 2);
            float bv = isC ? biasC[wr] : biasL[wr];
            int j = colp >> 2;
#pragma unroll
            for (int s = 0; s < 4; ++s) {
                float ii = 0.f, ff = 0.f, gg = 0.f, oo = 0.f;
#pragma unroll
                for (int r2 = 0; r2 < 4; ++r2) {
                    float v0 = acc[s][u][r2] + bv;
                    float x1 = __shfl_xor(v0, 1);
                    float x2 = __shfl_xor(v0, 2);
                    float x3 = __shfl_xor(v0, 3);
                    float iv = (q == 0) ? v0 : (q == 1) ? x1 : (q == 2) ? x2 : x3;
                    float fv = (q == 0) ? x1 : (q == 1) ? v0 : (q == 2) ? x3 : x2;
                    float gv = (q == 0) ? x2 : (q == 1) ? x3 : (q == 2) ? v0 : x1;
                    float ov = (q == 0) ? x3 : (q == 1) ? x2 : (q == 2) ? x1 : v0;
                    if (q == r2) { ii = iv; ff = fv; gg = gv; oo = ov; }
                }
                int row = row0 + s * 16 + (lane >> 4) * 4 + q;
                size_t ci = (size_t)row * 128 + j;
                float c2 = sigf(ff) * Cold[ci] + sigf(ii) * tanhf(gg);
                float h2 = sigf(oo) * tanhf(c2);
                Cnew[ci] = c2;
                short h = f2bf(h2);
                OH[ci] = h;
                OL[ci] = f2bf(h2 - bf2f(h));
            }
        }
    }
}

// ---------------------------------------------------------------------------
// Weight prep: zero-padded split into hi/lo bf16.
// ---------------------------------------------------------------------------
__global__ __launch_bounds__(256) void split_pad(
    const float* __restrict__ W, short* __restrict__ Wh, short* __restrict__ Wl,
    int rows, int cols, int prows, int pcols)
{
    int i = blockIdx.x * 256 + threadIdx.x;
    if (i >= prows * pcols) return;
    int r = i / pcols, c = i - r * pcols;
    float v = (r < rows && c < cols) ? W[(size_t)r * cols + c] : 0.f;
    short h = f2bf(v);
    Wh[i] = h;
    Wl[i] = f2bf(v - bf2f(h));
}

// ---------------------------------------------------------------------------
// SpMM gather: fp32 X in (exact — R2/R3 config gave absmax 0.0), fp32 acc,
// split-bf16 msgs out. 4 rows/block, 64 threads/row, 2 cols per thread.
// ---------------------------------------------------------------------------
__global__ __launch_bounds__(256) void spmm_kernel(
    const int* __restrict__ Lp, const int* __restrict__ Li,
    const int* __restrict__ Tp, const int* __restrict__ Ti,
    const float* __restrict__ X, short* __restrict__ mh, short* __restrict__ ml)
{
    const int r = blockIdx.x * 4 + (threadIdx.x >> 6);
    const int cp = (threadIdx.x & 63) * 2;
    if (r >= NRREAL) return;
    float s0 = 0.f, s1 = 0.f;
    if (r < NL) {
        int b = Lp[r], e = Lp[r + 1];
        int i = b;
        for (; i + 3 < e; i += 4) {
            float2 v0 = *(const float2*)&X[(size_t)(ROWC0 + Li[i]) * EMB + cp];
            float2 v1 = *(const float2*)&X[(size_t)(ROWC0 + Li[i + 1]) * EMB + cp];
            float2 v2 = *(const float2*)&X[(size_t)(ROWC0 + Li[i + 2]) * EMB + cp];
            float2 v3 = *(const float2*)&X[(size_t)(ROWC0 + Li[i + 3]) * EMB + cp];
            s0 += v0.x + v1.x + v2.x + v3.x;
            s1 += v0.y + v1.y + v2.y + v3.y;
        }
        for (; i < e; ++i) {
            float2 v = *(const float2*)&X[(size_t)(ROWC0 + Li[i]) * EMB + cp];
            s0 += v.x; s1 += v.y;
        }
    } else if (r >= ROWC0) {
        int c = r - ROWC0;
        int b = Tp[c], e = Tp[c + 1];
        int i = b;
        for (; i + 3 < e; i += 4) {
            float2 v0 = *(const float2*)&X[(size_t)Ti[i] * EMB + cp];
            float2 v1 = *(const float2*)&X[(size_t)Ti[i + 1] * EMB + cp];
            float2 v2 = *(const float2*)&X[(size_t)Ti[i + 2] * EMB + cp];
            float2 v3 = *(const float2*)&X[(size_t)Ti[i + 3] * EMB + cp];
            s0 += v0.x + v1.x + v2.x + v3.x;
            s1 += v0.y + v1.y + v2.y + v3.y;
        }
        for (; i < e; ++i) {
            float2 v = *(const float2*)&X[(size_t)Ti[i] * EMB + cp];
            s0 += v.x; s1 += v.y;
        }
    }
    size_t oi = (size_t)r * EMB + cp;
    short h0 = f2bf(s0), h1 = f2bf(s1);
    *(unsigned*)&mh[oi] = (unsigned)(unsigned short)h0 | ((unsigned)(unsigned short)h1 << 16);
    short l0 = f2bf(s0 - bf2f(h0)), l1 = f2bf(s1 - bf2f(h1));
    *(unsigned*)&ml[oi] = (unsigned)(unsigned short)l0 | ((unsigned)(unsigned short)l1 << 16);
}

__global__ __launch_bounds__(256) void init_states(
    const float* __restrict__ Li, const float* __restrict__ Ci,
    short* __restrict__ Hh, short* __restrict__ Hl, float* __restrict__ C,
    float* __restrict__ accum)
{
    size_t idx = (size_t)blockIdx.x * 256 + threadIdx.x;
    if (idx >= (size_t)NRP * EMB) return;
    int r = (int)(idx >> 7);
    int e = (int)(idx & 127);
    float h = 0.f;
    if (r < NL) h = Li[e];
    else if (r >= ROWC0 && r < NRREAL) h = Ci[e];
    short hh = f2bf(h);
    Hh[idx] = hh;
    Hl[idx] = f2bf(h - bf2f(hh));
    C[idx] = 0.f;
    if (idx == 0) accum[0] = 0.f;
}

// ---------------------------------------------------------------------------
// CSR build (verified rounds 1-3)
// ---------------------------------------------------------------------------
__global__ __launch_bounds__(256) void count_rows_L(const float* __restrict__ M, int* __restrict__ cnt)
{
    int l = blockIdx.x, t = threadIdx.x;
    int c_ = 0;
    for (int c = t; c < NC; c += 256) c_ += (M[(size_t)l * NC + c] != 0.f) ? 1 : 0;
#pragma unroll
    for (int off = 32; off > 0; off >>= 1) c_ += __shfl_down(c_, off);
    __shared__ int w[4];
    if ((t & 63) == 0) w[t >> 6] = c_;
    __syncthreads();
    if (t == 0) cnt[l] = w[0] + w[1] + w[2] + w[3];
}

__global__ __launch_bounds__(256) void scan_excl(const int* __restrict__ in, int* __restrict__ out, int n)
{
    const int t = threadIdx.x;
    const int per = (n + 255) >> 8;
    __shared__ int part[256];
    int s = 0;
    const int start = t * per;
    for (int i = 0; i < per; ++i) { int idx = start + i; if (idx < n) s += in[idx]; }
    part[t] = s;
    __syncthreads();
    for (int off = 1; off < 256; off <<= 1) {
        int v = (t >= off) ? part[t - off] : 0;
        __syncthreads();
        part[t] += v;
        __syncthreads();
    }
    int run = (t == 0) ? 0 : part[t - 1];
    for (int i = 0; i < per; ++i) {
        int idx = start + i;
        if (idx < n) { out[idx] = run; run += in[idx]; }
    }
    if (t == 255) out[n] = part[255];
}

__global__ __launch_bounds__(256) void fill_L(const float* __restrict__ M,
                                              const int* __restrict__ Lp, int* __restrict__ Lidx)
{
    int l = blockIdx.x, t = threadIdx.x, lane = t & 63, wid = t >> 6;
    __shared__ int wcnt[4];
    __shared__ int base;
    if (t == 0) base = Lp[l];
    __syncthreads();
    for (int c0 = 0; c0 < NC; c0 += 256) {
        int c = c0 + t;
        bool p = (c < NC) && (M[(size_t)l * NC + c] != 0.f);
        unsigned long long m = __ballot(p);
        if (lane == 0) wcnt[wid] = (int)__popcll(m);
        __syncthreads();
        int off = base;
        for (int w = 0; w < wid; ++w) off += wcnt[w];
        int rank = (int)__popcll(m & ((1ull << lane) - 1ull));
        if (p) Lidx[off + rank] = c;
        __syncthreads();
        if (t == 0) base += wcnt[0] + wcnt[1] + wcnt[2] + wcnt[3];
        __syncthreads();
    }
}

__global__ __launch_bounds__(256) void count_T(const float* __restrict__ M, int* __restrict__ cnt2d)
{
    int s = blockIdx.y;
    int c = blockIdx.x * 256 + threadIdx.x;
    if (c >= NC) return;
    int n = 0;
    int l0 = s * LCHUNK, l1 = l0 + LCHUNK;
    for (int l = l0; l < l1; ++l) n += (M[(size_t)l * NC + c] != 0.f) ? 1 : 0;
    cnt2d[(size_t)s * NC + c] = n;
}

__global__ __launch_bounds__(256) void colscan_T(const int* __restrict__ cnt2d,
                                                 int* __restrict__ cum2d, int* __restrict__ cntT)
{
    int c = blockIdx.x * 256 + threadIdx.x;
    if (c >= NC) return;
    int run = 0;
    for (int s = 0; s < NCHUNK; ++s) {
        cum2d[(size_t)s * NC + c] = run;
        run += cnt2d[(size_t)s * NC + c];
    }
    cntT[c] = run;
}

__global__ __launch_bounds__(256) void fill_T(const float* __restrict__ M,
                                              const int* __restrict__ Tp, const int* __restrict__ cum2d,
                                              int* __restrict__ Tidx)
{
    int s = blockIdx.y;
    int c = blockIdx.x * 256 + threadIdx.x;
    if (c >= NC) return;
    int pos = Tp[c] + cum2d[(size_t)s * NC + c];
    int l0 = s * LCHUNK, l1 = l0 + LCHUNK;
    for (int l = l0; l < l1; ++l) {
        if (M[(size_t)l * NC + c] != 0.f) Tidx[pos++] = l;
    }
}

// ---------------------------------------------------------------------------
// Vote epilogue
// ---------------------------------------------------------------------------
__global__ __launch_bounds__(256) void vote_reduce(
    const short* __restrict__ H2h, const short* __restrict__ H2l,
    const float* __restrict__ W3, const float* __restrict__ b3, float* __restrict__ accum)
{
    int wid = threadIdx.x >> 6, lane = threadIdx.x & 63;
    int r = blockIdx.x * 4 + wid;
    float s = 0.f;
    if (r < NL) {
        const short* xh = &H2h[(size_t)r * 224];
        const short* xl = &H2l[(size_t)r * 224];
        for (int k = lane; k < 200; k += 64) s += (bf2f(xh[k]) + bf2f(xl[k])) * W3[k];
    }
#pragma unroll
    for (int off = 32; off > 0; off >>= 1) s += __shfl_down(s, off);
    if (lane == 0 && r < NL) {
        float v = 1.f / (1.f + expf(-(s + b3[0])));
        atomicAdd(accum, v);
    }
}

__global__ void finalize_logit(const float* __restrict__ accum, float* __restrict__ out)
{
    float avg = accum[0] / (float)NL;
    out[0] = logf(avg / (1.f - avg));
}

// ---------------------------------------------------------------------------
// Host launcher
// ---------------------------------------------------------------------------
extern "C" void kernel_launch(void* const* d_in, const int* in_sizes, int n_in,
                              void* d_out, int out_size, void* d_ws, size_t ws_size,
                              hipStream_t stream)
{
    const float* M      = (const float*)d_in[0];
    const float* L_init = (const float*)d_in[1];
    const float* C_init = (const float*)d_in[2];
    const float* LC_W1 = (const float*)d_in[3];  const float* LC_b1 = (const float*)d_in[4];
    const float* LC_W2 = (const float*)d_in[5];  const float* LC_b2 = (const float*)d_in[6];
    const float* LC_W3 = (const float*)d_in[7];  const float* LC_b3 = (const float*)d_in[8];
    const float* CL_W1 = (const float*)d_in[9];  const float* CL_b1 = (const float*)d_in[10];
    const float* CL_W2 = (const float*)d_in[11]; const float* CL_b2 = (const float*)d_in[12];
    const float* CL_W3 = (const float*)d_in[13]; const float* CL_b3 = (const float*)d_in[14];
    const float* L_Wih = (const float*)d_in[15]; const float* L_Whh = (const float*)d_in[16];
    const float* L_b   = (const float*)d_in[17];
    const float* C_Wih = (const float*)d_in[18]; const float* C_Whh = (const float*)d_in[19];
    const float* C_b   = (const float*)d_in[20];
    const float* V_W1 = (const float*)d_in[21]; const float* V_b1 = (const float*)d_in[22];
    const float* V_W2 = (const float*)d_in[23]; const float* V_b2 = (const float*)d_in[24];
    const float* V_W3 = (const float*)d_in[25]; const float* V_b3 = (const float*)d_in[26];
    float* out = (float*)d_out;

    char* ws = (char*)d_ws;
    size_t off = 0;
    auto alloc = [&](size_t bytes) -> void* {
        void* p = ws + off;
        off += (bytes + 255) & ~(size_t)255;
        return p;
    };
    const size_t NE = (size_t)NRP * EMB;
    short* HAh = (short*)alloc(NE * 2); short* HAl = (short*)alloc(NE * 2);
    short* HBh = (short*)alloc(NE * 2); short* HBl = (short*)alloc(NE * 2);
    float* CA = (float*)alloc(NE * 4);  float* CB = (float*)alloc(NE * 4);
    short* msgsH = (short*)alloc(NE * 2); short* msgsL = (short*)alloc(NE * 2);
    float* X    = (float*)alloc(NE * 4);
    short* H1h = (short*)alloc((size_t)NRP * 416 * 2); short* H1l = (short*)alloc((size_t)NRP * 416 * 2);
    short* H2h = (short*)alloc((size_t)NRP * 224 * 2); short* H2l = (short*)alloc((size_t)NRP * 224 * 2);
    float* accum = (float*)alloc(256);
    // split/padded weights
    short* W1hL = (short*)alloc(448 * 128 * 2); short* W1lL = (short*)alloc(448 * 128 * 2);
    short* W1hC = (short*)alloc(448 * 128 * 2); short* W1lC = (short*)alloc(448 * 128 * 2);
    short* W2hL = (short*)alloc(256 * 416 * 2); short* W2lL = (short*)alloc(256 * 416 * 2);
    short* W2hC = (short*)alloc(256 * 416 * 2); short* W2lC = (short*)alloc(256 * 416 * 2);
    short* W3hL = (short*)alloc(128 * 224 * 2); short* W3lL = (short*)alloc(128 * 224 * 2);
    short* W3hC = (short*)alloc(128 * 224 * 2); short* W3lC = (short*)alloc(128 * 224 * 2);
    short* WihhL = (short*)alloc(512 * 128 * 2); short* WihlL = (short*)alloc(512 * 128 * 2);
    short* WhhhL = (short*)alloc(512 * 128 * 2); short* WhhlL = (short*)alloc(512 * 128 * 2);
    short* WihhC = (short*)alloc(512 * 128 * 2); short* WihlC = (short*)alloc(512 * 128 * 2);
    short* WhhhC = (short*)alloc(512 * 128 * 2); short* WhhlC = (short*)alloc(512 * 128 * 2);
    short* V1h = (short*)alloc(448 * 128 * 2); short* V1l = (short*)alloc(448 * 128 * 2);
    short* V2h = (short*)alloc(256 * 416 * 2); short* V2l = (short*)alloc(256 * 416 * 2);
    // CSR
    int* Lp   = (int*)alloc(4104 * 4);
    int* Tp   = (int*)alloc(8104 * 4);
    int* Lidx = (int*)alloc(1000000 * 4);
    int* Tidx = (int*)alloc(1000000 * 4);
    int* cnt2d = (int*)alloc((size_t)NCHUNK * NC * 4);
    int* cum2d = (int*)alloc((size_t)NCHUNK * NC * 4);
    int* cntL = (int*)alloc(4096 * 4);
    int* cntT = (int*)alloc(8192 * 4);
    (void)ws_size; (void)in_sizes; (void)n_in; (void)out_size;

    // --- CSR build ---
    count_rows_L<<<NL, 256, 0, stream>>>(M, cntL);
    scan_excl<<<1, 256, 0, stream>>>(cntL, Lp, NL);
    fill_L<<<NL, 256, 0, stream>>>(M, Lp, Lidx);
    {
        dim3 g((NC + 255) / 256, NCHUNK);
        count_T<<<g, 256, 0, stream>>>(M, cnt2d);
        colscan_T<<<(NC + 255) / 256, 256, 0, stream>>>(cnt2d, cum2d, cntT);
        scan_excl<<<1, 256, 0, stream>>>(cntT, Tp, NC);
        fill_T<<<g, 256, 0, stream>>>(M, Tp, cum2d, Tidx);
    }

    // --- weight split/pad ---
    auto sp = [&](const float* W, short* Wh, short* Wl, int r, int c, int pr, int pc) {
        split_pad<<<(pr * pc + 255) / 256, 256, 0, stream>>>(W, Wh, Wl, r, c, pr, pc);
    };
    sp(LC_W1, W1hL, W1lL, 400, 128, 448, 128);
    sp(CL_W1, W1hC, W1lC, 400, 128, 448, 128);
    sp(LC_W2, W2hL, W2lL, 200, 400, 256, 416);
    sp(CL_W2, W2hC, W2lC, 200, 400, 256, 416);
    sp(LC_W3, W3hL, W3lL, 128, 200, 128, 224);
    sp(CL_W3, W3hC, W3lC, 128, 200, 128, 224);
    sp(L_Wih, WihhL, WihlL, 512, 128, 512, 128);
    sp(L_Whh, WhhhL, WhhlL, 512, 128, 512, 128);
    sp(C_Wih, WihhC, WihlC, 512, 128, 512, 128);
    sp(C_Whh, WhhhC, WhhlC, 512, 128, 512, 128);
    sp(V_W1, V1h, V1l, 400, 128, 448, 128);
    sp(V_W2, V2h, V2l, 200, 400, 256, 416);

    const int nelem_blocks = (int)((NE + 255) / 256);
    init_states<<<nelem_blocks, 256, 0, stream>>>(L_init, C_init, HAh, HAl, CA, accum);

    // --- 30 message-passing steps (5 kernels each) ---
    short *Hch = HAh, *Hcl = HAl, *Hnh = HBh, *Hnl = HBl;
    float *Ccur = CA, *Cnxt = CB;
    const int RT = NRP / 64;  // 192 row tiles
    for (int step = 0; step < TSTEPS; ++step) {
        gemm64<128, 1, false, true, false><<<dim3(7, RT), 64, 0, stream>>>(
            Hch, Hcl, nullptr, nullptr,
            W1hL, W1lL, W1hC, W1lC, nullptr, nullptr, nullptr, nullptr,
            LC_b1, CL_b1, H1h, H1l, nullptr, nullptr, nullptr, 400, 416);
        gemm64<416, 1, false, true, false><<<dim3(4, RT), 64, 0, stream>>>(
            H1h, H1l, nullptr, nullptr,
            W2hL, W2lL, W2hC, W2lC, nullptr, nullptr, nullptr, nullptr,
            LC_b2, CL_b2, H2h, H2l, nullptr, nullptr, nullptr, 200, 224);
        gemm64<224, 0, false, false, false><<<dim3(2, RT), 64, 0, stream>>>(
            H2h, H2l, nullptr, nullptr,
            W3hL, W3lL, W3hC, W3lC, nullptr, nullptr, nullptr, nullptr,
            LC_b3, CL_b3, nullptr, nullptr, X, nullptr, nullptr, 128, 128);
        spmm_kernel<<<(NRREAL + 3) / 4, 256, 0, stream>>>(Lp, Lidx, Tp, Tidx, X, msgsH, msgsL);
        gemm64<128, 3, true, false, true><<<dim3(8, RT), 64, 0, stream>>>(
            msgsH, msgsL, Hch, Hcl,
            WihhL, WihlL, WihhC, WihlC, WhhhL, WhhlL, WhhhC, WhhlC,
            L_b, C_b, Hnh, Hnl, nullptr, Ccur, Cnxt, 512, 512);
        short* th = Hch; Hch = Hnh; Hnh = th;
        short* tl = Hcl; Hcl = Hnl; Hnl = tl;
        float* tc = Ccur; Ccur = Cnxt; Cnxt = tc;
    }

    // --- vote MLP + logit (lit rows only: 64 row tiles of 64) ---
    gemm64<128, 1, false, true, false><<<dim3(7, 64), 64, 0, stream>>>(
        Hch, Hcl, nullptr, nullptr,
        V1h, V1l, V1h, V1l, nullptr, nullptr, nullptr, nullptr,
        V_b1, V_b1, H1h, H1l, nullptr, nullptr, nullptr, 400, 416);
    gemm64<416, 1, false, true, false><<<dim3(4, 64), 64, 0, stream>>>(
        H1h, H1l, nullptr, nullptr,
        V2h, V2l, V2h, V2l, nullptr, nullptr, nullptr, nullptr,
        V_b2, V_b2, H2h, H2l, nullptr, nullptr, nullptr, 200, 224);
    vote_reduce<<<(NL + 3) / 4, 256, 0, stream>>>(H2h, H2l, V_W3, V_b3, accum);
    finalize_logit<<<1, 1, 0, stream>>>(accum, out);
}

// Round 6
// 4409.660 us; speedup vs baseline: 1.3031x; 1.3031x over previous
//
#include <hip/hip_runtime.h>

#define NL 4000
#define NC 8000
#define EMB 128
#define ROWC0 4096           // clause region start
#define NRP 12288            // padded total rows (96 x 128)
#define NRREAL (ROWC0 + NC)  // 12096 rows with data
#define TSTEPS 30
#define LCHUNK 80
#define NCHUNK 50

typedef __attribute__((ext_vector_type(8))) short bf16x8;
typedef __attribute__((ext_vector_type(4))) float f32x4;

__device__ __forceinline__ short f2bf(float x) {
    union { float f; unsigned u; } v; v.f = x;
    unsigned r = v.u + 0x7fffu + ((v.u >> 16) & 1u);
    return (short)(r >> 16);
}
__device__ __forceinline__ float bf2f(short s) {
    union { unsigned u; float f; } v; v.u = ((unsigned)(unsigned short)s) << 16;
    return v.f;
}
__device__ __forceinline__ float sigf(float x) { return 1.f / (1.f + expf(-x)); }

__device__ __forceinline__ void gload16(const void* g, void* l) {
    __builtin_amdgcn_global_load_lds(
        (const __attribute__((address_space(1))) unsigned int*)g,
        (__attribute__((address_space(3))) unsigned int*)l, 16, 0, 0);
}

// ---------------------------------------------------------------------------
// Split-bf16 MFMA GEMM, 2-stage pipelined double-buffered K-loop (R3 struct,
// measured fastest). product = Ah*Wh + Ah*Wl + Al*Wh in fp32 acc.
// OUTM: 0 = fp32 out, 1 = split-bf16 out (+relu), 3 = fused LSTM epilogue
// (gate-space pre-permuted weights: out col 4j+g = gate g of cell dim j;
// shfl_xor{1,2,3} quad-gather -> per-lane complete (i,f,g,o); verified exact
// in R5). Rows < ROWC0 use the L weight set, else the C set.
// ---------------------------------------------------------------------------
template<int BM_, int BN_, int KS, int OUTM, bool TWOA, bool RELU>
__global__ __launch_bounds__((BM_/64)*(BN_/64)*64) void mfma_gemm(
    const short* __restrict__ A1h, const short* __restrict__ A1l,
    const short* __restrict__ A2h, const short* __restrict__ A2l,
    const short* __restrict__ B1hL, const short* __restrict__ B1lL,
    const short* __restrict__ B1hC, const short* __restrict__ B1lC,
    const short* __restrict__ B2hL, const short* __restrict__ B2lL,
    const short* __restrict__ B2hC, const short* __restrict__ B2lC,
    const float* __restrict__ biasL, const float* __restrict__ biasC,
    short* __restrict__ OH, short* __restrict__ OL, float* __restrict__ OF,
    const float* __restrict__ Cold, float* __restrict__ Cnew,
    int Freal, int Fstore)
{
    constexpr int T = (BM_/64)*(BN_/64)*64;
    constexpr int KIT = KS / 32;
    constexpr int NIT = (TWOA ? 2 : 1) * KIT;

    __shared__ short sAh[2][BM_*32];
    __shared__ short sAl[2][BM_*32];
    __shared__ short sBh[2][BN_*32];
    __shared__ short sBl[2][BN_*32];

    const int row0 = blockIdx.y * BM_;
    const int c0 = blockIdx.x * BN_;
    const bool isC = (row0 >= ROWC0);
    const int t = threadIdx.x;
    const int lane = t & 63;
    const int w = t >> 6;
    constexpr int WCn = BN_/64;
    const int wr = w / WCn, wc = w % WCn;
    const int l15 = lane & 15;

    f32x4 acc[4][4] = {};

    auto stage = [&](int buf, int it) {
        const int ph = it / KIT;
        const int kc = (it - ph * KIT) * 32;
        const short *Ah, *Al, *Bh, *Bl;
        if (TWOA && ph) {
            Ah = A2h; Al = A2l;
            Bh = isC ? B2hC : B2hL; Bl = isC ? B2lC : B2lL;
        } else {
            Ah = A1h; Al = A1l;
            Bh = isC ? B1hC : B1hL; Bl = isC ? B1lC : B1lL;
        }
#pragma unroll
        for (int q = 0; q < BM_*4/T; ++q) {
            int c = q * T + t;
            int row = c >> 2, slot = c & 3;
            int gk = kc + ((slot ^ ((row >> 1) & 3)) << 3);
            size_t gi = (size_t)(row0 + row) * KS + gk;
            gload16(Ah + gi, &sAh[buf][c * 8]);
            gload16(Al + gi, &sAl[buf][c * 8]);
        }
#pragma unroll
        for (int q = 0; q < BN_*4/T; ++q) {
            int c = q * T + t;
            int row = c >> 2, slot = c & 3;
            int gk = kc + ((slot ^ ((row >> 1) & 3)) << 3);
            size_t gi = (size_t)(c0 + row) * KS + gk;
            gload16(Bh + gi, &sBh[buf][c * 8]);
            gload16(Bl + gi, &sBl[buf][c * 8]);
        }
    };

    // prologue
    stage(0, 0);
    asm volatile("s_waitcnt vmcnt(0)" ::: "memory");
    __syncthreads();

    int cur = 0;
    for (int it = 0; it < NIT; ++it) {
        if (it + 1 < NIT) stage(cur ^ 1, it + 1);   // loads fly under MFMAs

        bf16x8 af[4][2], bfr[4][2];
#pragma unroll
        for (int s = 0; s < 4; ++s) {
            int row = wr * 64 + s * 16 + l15;
            int slot = (lane >> 4) ^ ((row >> 1) & 3);
            int idx = row * 32 + slot * 8;
            af[s][0] = *(const bf16x8*)&sAh[cur][idx];
            af[s][1] = *(const bf16x8*)&sAl[cur][idx];
            int colr = wc * 64 + s * 16 + l15;
            int slotb = (lane >> 4) ^ ((colr >> 1) & 3);
            int idxb = colr * 32 + slotb * 8;
            bfr[s][0] = *(const bf16x8*)&sBh[cur][idxb];
            bfr[s][1] = *(const bf16x8*)&sBl[cur][idxb];
        }
#pragma unroll
        for (int s = 0; s < 4; ++s)
#pragma unroll
            for (int u = 0; u < 4; ++u) {
                acc[s][u] = __builtin_amdgcn_mfma_f32_16x16x32_bf16(af[s][0], bfr[u][0], acc[s][u], 0, 0, 0);
                acc[s][u] = __builtin_amdgcn_mfma_f32_16x16x32_bf16(af[s][0], bfr[u][1], acc[s][u], 0, 0, 0);
                acc[s][u] = __builtin_amdgcn_mfma_f32_16x16x32_bf16(af[s][1], bfr[u][0], acc[s][u], 0, 0, 0);
            }

        if (it + 1 < NIT) {
            asm volatile("s_waitcnt vmcnt(0)" ::: "memory");
            __syncthreads();
            cur ^= 1;
        }
    }

    if (OUTM != 3) {
        // C/D frag layout: col = lane&15, row = (lane>>4)*4 + reg (m89)
#pragma unroll
        for (int u = 0; u < 4; ++u) {
            int col = c0 + wc * 64 + u * 16 + l15;
            if (col >= Fstore) continue;
            float bv = (col < Freal) ? (isC ? biasC[col] : biasL[col]) : 0.f;
#pragma unroll
            for (int s = 0; s < 4; ++s) {
#pragma unroll
                for (int j = 0; j < 4; ++j) {
                    int row = row0 + wr * 64 + s * 16 + (lane >> 4) * 4 + j;
                    float v = acc[s][u][j] + bv;
                    if (RELU) v = fmaxf(v, 0.f);
                    size_t oi = (size_t)row * Fstore + col;
                    if (OUTM == 1) {
                        short h = f2bf(v);
                        OH[oi] = h;
                        OL[oi] = f2bf(v - bf2f(h));
                    } else {
                        OF[oi] = v;
                    }
                }
            }
        }
    } else {
        // Fused LSTM epilogue (R5-verified). colp = permuted gate col 4j+g.
        const int q = lane & 3;
#pragma unroll
        for (int u = 0; u < 4; ++u) {
            int colp = c0 + wc * 64 + u * 16 + l15;
            int wrr = (colp & 3) * 128 + (colp >> 2);   // original gate row (bias)
            float bv = isC ? biasC[wrr] : biasL[wrr];
            int j = colp >> 2;
#pragma unroll
            for (int s = 0; s < 4; ++s) {
                float ii = 0.f, ff = 0.f, gg = 0.f, oo = 0.f;
#pragma unroll
                for (int r2 = 0; r2 < 4; ++r2) {
                    float v0 = acc[s][u][r2] + bv;
                    float x1 = __shfl_xor(v0, 1);
                    float x2 = __shfl_xor(v0, 2);
                    float x3 = __shfl_xor(v0, 3);
                    float iv = (q == 0) ? v0 : (q == 1) ? x1 : (q == 2) ? x2 : x3;
                    float fv = (q == 0) ? x1 : (q == 1) ? v0 : (q == 2) ? x3 : x2;
                    float gv = (q == 0) ? x2 : (q == 1) ? x3 : (q == 2) ? v0 : x1;
                    float ov = (q == 0) ? x3 : (q == 1) ? x2 : (q == 2) ? x1 : v0;
                    if (q == r2) { ii = iv; ff = fv; gg = gv; oo = ov; }
                }
                int row = row0 + wr * 64 + s * 16 + (lane >> 4) * 4 + q;
                size_t ci = (size_t)row * 128 + j;
                float c2 = sigf(ff) * Cold[ci] + sigf(ii) * tanhf(gg);
                float h2 = sigf(oo) * tanhf(c2);
                Cnew[ci] = c2;
                short h = f2bf(h2);
                OH[ci] = h;
                OL[ci] = f2bf(h2 - bf2f(h));
            }
        }
    }
}

// ---------------------------------------------------------------------------
// Weight prep: zero-padded split into hi/lo bf16. PERM=true applies the
// LSTM gate permutation: output row p holds input row ((p&3)<<7)|(p>>2).
// ---------------------------------------------------------------------------
template<bool PERM>
__global__ __launch_bounds__(256) void split_pad(
    const float* __restrict__ W, short* __restrict__ Wh, short* __restrict__ Wl,
    int rows, int cols, int prows, int pcols)
{
    int i = blockIdx.x * 256 + threadIdx.x;
    if (i >= prows * pcols) return;
    int p = i / pcols, c = i - p * pcols;
    int r = PERM ? (((p & 3) << 7) | (p >> 2)) : p;
    float v = (r < rows && c < cols) ? W[(size_t)r * cols + c] : 0.f;
    short h = f2bf(v);
    Wh[i] = h;
    Wl[i] = f2bf(v - bf2f(h));
}

// ---------------------------------------------------------------------------
// SpMM gather: fp32 X in (exact), fp32 acc, split-bf16 msgs out.
// 4 rows/block, 64 threads/row, 2 cols per thread (R5-verified).
// ---------------------------------------------------------------------------
__global__ __launch_bounds__(256) void spmm_kernel(
    const int* __restrict__ Lp, const int* __restrict__ Li,
    const int* __restrict__ Tp, const int* __restrict__ Ti,
    const float* __restrict__ X, short* __restrict__ mh, short* __restrict__ ml)
{
    const int r = blockIdx.x * 4 + (threadIdx.x >> 6);
    const int cp = (threadIdx.x & 63) * 2;
    if (r >= NRREAL) return;
    float s0 = 0.f, s1 = 0.f;
    if (r < NL) {
        int b = Lp[r], e = Lp[r + 1];
        int i = b;
        for (; i + 3 < e; i += 4) {
            float2 v0 = *(const float2*)&X[(size_t)(ROWC0 + Li[i]) * EMB + cp];
            float2 v1 = *(const float2*)&X[(size_t)(ROWC0 + Li[i + 1]) * EMB + cp];
            float2 v2 = *(const float2*)&X[(size_t)(ROWC0 + Li[i + 2]) * EMB + cp];
            float2 v3 = *(const float2*)&X[(size_t)(ROWC0 + Li[i + 3]) * EMB + cp];
            s0 += v0.x + v1.x + v2.x + v3.x;
            s1 += v0.y + v1.y + v2.y + v3.y;
        }
        for (; i < e; ++i) {
            float2 v = *(const float2*)&X[(size_t)(ROWC0 + Li[i]) * EMB + cp];
            s0 += v.x; s1 += v.y;
        }
    } else if (r >= ROWC0) {
        int c = r - ROWC0;
        int b = Tp[c], e = Tp[c + 1];
        int i = b;
        for (; i + 3 < e; i += 4) {
            float2 v0 = *(const float2*)&X[(size_t)Ti[i] * EMB + cp];
            float2 v1 = *(const float2*)&X[(size_t)Ti[i + 1] * EMB + cp];
            float2 v2 = *(const float2*)&X[(size_t)Ti[i + 2] * EMB + cp];
            float2 v3 = *(const float2*)&X[(size_t)Ti[i + 3] * EMB + cp];
            s0 += v0.x + v1.x + v2.x + v3.x;
            s1 += v0.y + v1.y + v2.y + v3.y;
        }
        for (; i < e; ++i) {
            float2 v = *(const float2*)&X[(size_t)Ti[i] * EMB + cp];
            s0 += v.x; s1 += v.y;
        }
    }
    size_t oi = (size_t)r * EMB + cp;
    short h0 = f2bf(s0), h1 = f2bf(s1);
    *(unsigned*)&mh[oi] = (unsigned)(unsigned short)h0 | ((unsigned)(unsigned short)h1 << 16);
    short l0 = f2bf(s0 - bf2f(h0)), l1 = f2bf(s1 - bf2f(h1));
    *(unsigned*)&ml[oi] = (unsigned)(unsigned short)l0 | ((unsigned)(unsigned short)l1 << 16);
}

__global__ __launch_bounds__(256) void init_states(
    const float* __restrict__ Li, const float* __restrict__ Ci,
    short* __restrict__ Hh, short* __restrict__ Hl, float* __restrict__ C,
    float* __restrict__ accum)
{
    size_t idx = (size_t)blockIdx.x * 256 + threadIdx.x;
    if (idx >= (size_t)NRP * EMB) return;
    int r = (int)(idx >> 7);
    int e = (int)(idx & 127);
    float h = 0.f;
    if (r < NL) h = Li[e];
    else if (r >= ROWC0 && r < NRREAL) h = Ci[e];
    short hh = f2bf(h);
    Hh[idx] = hh;
    Hl[idx] = f2bf(h - bf2f(hh));
    C[idx] = 0.f;
    if (idx == 0) accum[0] = 0.f;
}

// ---------------------------------------------------------------------------
// CSR build (verified rounds 1-5)
// ---------------------------------------------------------------------------
__global__ __launch_bounds__(256) void count_rows_L(const float* __restrict__ M, int* __restrict__ cnt)
{
    int l = blockIdx.x, t = threadIdx.x;
    int c_ = 0;
    for (int c = t; c < NC; c += 256) c_ += (M[(size_t)l * NC + c] != 0.f) ? 1 : 0;
#pragma unroll
    for (int off = 32; off > 0; off >>= 1) c_ += __shfl_down(c_, off);
    __shared__ int w[4];
    if ((t & 63) == 0) w[t >> 6] = c_;
    __syncthreads();
    if (t == 0) cnt[l] = w[0] + w[1] + w[2] + w[3];
}

__global__ __launch_bounds__(256) void scan_excl(const int* __restrict__ in, int* __restrict__ out, int n)
{
    const int t = threadIdx.x;
    const int per = (n + 255) >> 8;
    __shared__ int part[256];
    int s = 0;
    const int start = t * per;
    for (int i = 0; i < per; ++i) { int idx = start + i; if (idx < n) s += in[idx]; }
    part[t] = s;
    __syncthreads();
    for (int off = 1; off < 256; off <<= 1) {
        int v = (t >= off) ? part[t - off] : 0;
        __syncthreads();
        part[t] += v;
        __syncthreads();
    }
    int run = (t == 0) ? 0 : part[t - 1];
    for (int i = 0; i < per; ++i) {
        int idx = start + i;
        if (idx < n) { out[idx] = run; run += in[idx]; }
    }
    if (t == 255) out[n] = part[255];
}

__global__ __launch_bounds__(256) void fill_L(const float* __restrict__ M,
                                              const int* __restrict__ Lp, int* __restrict__ Lidx)
{
    int l = blockIdx.x, t = threadIdx.x, lane = t & 63, wid = t >> 6;
    __shared__ int wcnt[4];
    __shared__ int base;
    if (t == 0) base = Lp[l];
    __syncthreads();
    for (int c0 = 0; c0 < NC; c0 += 256) {
        int c = c0 + t;
        bool p = (c < NC) && (M[(size_t)l * NC + c] != 0.f);
        unsigned long long m = __ballot(p);
        if (lane == 0) wcnt[wid] = (int)__popcll(m);
        __syncthreads();
        int off = base;
        for (int w = 0; w < wid; ++w) off += wcnt[w];
        int rank = (int)__popcll(m & ((1ull << lane) - 1ull));
        if (p) Lidx[off + rank] = c;
        __syncthreads();
        if (t == 0) base += wcnt[0] + wcnt[1] + wcnt[2] + wcnt[3];
        __syncthreads();
    }
}

__global__ __launch_bounds__(256) void count_T(const float* __restrict__ M, int* __restrict__ cnt2d)
{
    int s = blockIdx.y;
    int c = blockIdx.x * 256 + threadIdx.x;
    if (c >= NC) return;
    int n = 0;
    int l0 = s * LCHUNK, l1 = l0 + LCHUNK;
    for (int l = l0; l < l1; ++l) n += (M[(size_t)l * NC + c] != 0.f) ? 1 : 0;
    cnt2d[(size_t)s * NC + c] = n;
}

__global__ __launch_bounds__(256) void colscan_T(const int* __restrict__ cnt2d,
                                                 int* __restrict__ cum2d, int* __restrict__ cntT)
{
    int c = blockIdx.x * 256 + threadIdx.x;
    if (c >= NC) return;
    int run = 0;
    for (int s = 0; s < NCHUNK; ++s) {
        cum2d[(size_t)s * NC + c] = run;
        run += cnt2d[(size_t)s * NC + c];
    }
    cntT[c] = run;
}

__global__ __launch_bounds__(256) void fill_T(const float* __restrict__ M,
                                              const int* __restrict__ Tp, const int* __restrict__ cum2d,
                                              int* __restrict__ Tidx)
{
    int s = blockIdx.y;
    int c = blockIdx.x * 256 + threadIdx.x;
    if (c >= NC) return;
    int pos = Tp[c] + cum2d[(size_t)s * NC + c];
    int l0 = s * LCHUNK, l1 = l0 + LCHUNK;
    for (int l = l0; l < l1; ++l) {
        if (M[(size_t)l * NC + c] != 0.f) Tidx[pos++] = l;
    }
}

// ---------------------------------------------------------------------------
// Vote epilogue
// ---------------------------------------------------------------------------
__global__ __launch_bounds__(256) void vote_reduce(
    const short* __restrict__ H2h, const short* __restrict__ H2l,
    const float* __restrict__ W3, const float* __restrict__ b3, float* __restrict__ accum)
{
    int wid = threadIdx.x >> 6, lane = threadIdx.x & 63;
    int r = blockIdx.x * 4 + wid;
    float s = 0.f;
    if (r < NL) {
        const short* xh = &H2h[(size_t)r * 224];
        const short* xl = &H2l[(size_t)r * 224];
        for (int k = lane; k < 200; k += 64) s += (bf2f(xh[k]) + bf2f(xl[k])) * W3[k];
    }
#pragma unroll
    for (int off = 32; off > 0; off >>= 1) s += __shfl_down(s, off);
    if (lane == 0 && r < NL) {
        float v = 1.f / (1.f + expf(-(s + b3[0])));
        atomicAdd(accum, v);
    }
}

__global__ void finalize_logit(const float* __restrict__ accum, float* __restrict__ out)
{
    float avg = accum[0] / (float)NL;
    out[0] = logf(avg / (1.f - avg));
}

// ---------------------------------------------------------------------------
// Host launcher
// ---------------------------------------------------------------------------
extern "C" void kernel_launch(void* const* d_in, const int* in_sizes, int n_in,
                              void* d_out, int out_size, void* d_ws, size_t ws_size,
                              hipStream_t stream)
{
    const float* M      = (const float*)d_in[0];
    const float* L_init = (const float*)d_in[1];
    const float* C_init = (const float*)d_in[2];
    const float* LC_W1 = (const float*)d_in[3];  const float* LC_b1 = (const float*)d_in[4];
    const float* LC_W2 = (const float*)d_in[5];  const float* LC_b2 = (const float*)d_in[6];
    const float* LC_W3 = (const float*)d_in[7];  const float* LC_b3 = (const float*)d_in[8];
    const float* CL_W1 = (const float*)d_in[9];  const float* CL_b1 = (const float*)d_in[10];
    const float* CL_W2 = (const float*)d_in[11]; const float* CL_b2 = (const float*)d_in[12];
    const float* CL_W3 = (const float*)d_in[13]; const float* CL_b3 = (const float*)d_in[14];
    const float* L_Wih = (const float*)d_in[15]; const float* L_Whh = (const float*)d_in[16];
    const float* L_b   = (const float*)d_in[17];
    const float* C_Wih = (const float*)d_in[18]; const float* C_Whh = (const float*)d_in[19];
    const float* C_b   = (const float*)d_in[20];
    const float* V_W1 = (const float*)d_in[21]; const float* V_b1 = (const float*)d_in[22];
    const float* V_W2 = (const float*)d_in[23]; const float* V_b2 = (const float*)d_in[24];
    const float* V_W3 = (const float*)d_in[25]; const float* V_b3 = (const float*)d_in[26];
    float* out = (float*)d_out;

    char* ws = (char*)d_ws;
    size_t off = 0;
    auto alloc = [&](size_t bytes) -> void* {
        void* p = ws + off;
        off += (bytes + 255) & ~(size_t)255;
        return p;
    };
    const size_t NE = (size_t)NRP * EMB;
    short* HAh = (short*)alloc(NE * 2); short* HAl = (short*)alloc(NE * 2);
    short* HBh = (short*)alloc(NE * 2); short* HBl = (short*)alloc(NE * 2);
    float* CA = (float*)alloc(NE * 4);  float* CB = (float*)alloc(NE * 4);
    short* msgsH = (short*)alloc(NE * 2); short* msgsL = (short*)alloc(NE * 2);
    float* X    = (float*)alloc(NE * 4);
    short* H1h = (short*)alloc((size_t)NRP * 416 * 2); short* H1l = (short*)alloc((size_t)NRP * 416 * 2);
    short* H2h = (short*)alloc((size_t)NRP * 224 * 2); short* H2l = (short*)alloc((size_t)NRP * 224 * 2);
    float* accum = (float*)alloc(256);
    // split/padded weights (B-tile rows padded to 128-multiples)
    short* W1hL = (short*)alloc(512 * 128 * 2); short* W1lL = (short*)alloc(512 * 128 * 2);
    short* W1hC = (short*)alloc(512 * 128 * 2); short* W1lC = (short*)alloc(512 * 128 * 2);
    short* W2hL = (short*)alloc(256 * 416 * 2); short* W2lL = (short*)alloc(256 * 416 * 2);
    short* W2hC = (short*)alloc(256 * 416 * 2); short* W2lC = (short*)alloc(256 * 416 * 2);
    short* W3hL = (short*)alloc(128 * 224 * 2); short* W3lL = (short*)alloc(128 * 224 * 2);
    short* W3hC = (short*)alloc(128 * 224 * 2); short* W3lC = (short*)alloc(128 * 224 * 2);
    short* WihhL = (short*)alloc(512 * 128 * 2); short* WihlL = (short*)alloc(512 * 128 * 2);
    short* WhhhL = (short*)alloc(512 * 128 * 2); short* WhhlL = (short*)alloc(512 * 128 * 2);
    short* WihhC = (short*)alloc(512 * 128 * 2); short* WihlC = (short*)alloc(512 * 128 * 2);
    short* WhhhC = (short*)alloc(512 * 128 * 2); short* WhhlC = (short*)alloc(512 * 128 * 2);
    short* V1h = (short*)alloc(512 * 128 * 2); short* V1l = (short*)alloc(512 * 128 * 2);
    short* V2h = (short*)alloc(256 * 416 * 2); short* V2l = (short*)alloc(256 * 416 * 2);
    // CSR
    int* Lp   = (int*)alloc(4104 * 4);
    int* Tp   = (int*)alloc(8104 * 4);
    int* Lidx = (int*)alloc(1000000 * 4);
    int* Tidx = (int*)alloc(1000000 * 4);
    int* cnt2d = (int*)alloc((size_t)NCHUNK * NC * 4);
    int* cum2d = (int*)alloc((size_t)NCHUNK * NC * 4);
    int* cntL = (int*)alloc(4096 * 4);
    int* cntT = (int*)alloc(8192 * 4);
    (void)ws_size; (void)in_sizes; (void)n_in; (void)out_size;

    // --- CSR build ---
    count_rows_L<<<NL, 256, 0, stream>>>(M, cntL);
    scan_excl<<<1, 256, 0, stream>>>(cntL, Lp, NL);
    fill_L<<<NL, 256, 0, stream>>>(M, Lp, Lidx);
    {
        dim3 g((NC + 255) / 256, NCHUNK);
        count_T<<<g, 256, 0, stream>>>(M, cnt2d);
        colscan_T<<<(NC + 255) / 256, 256, 0, stream>>>(cnt2d, cum2d, cntT);
        scan_excl<<<1, 256, 0, stream>>>(cntT, Tp, NC);
        fill_T<<<g, 256, 0, stream>>>(M, Tp, cum2d, Tidx);
    }

    // --- weight split/pad ---
    auto sp = [&](const float* W, short* Wh, short* Wl, int r, int c, int pr, int pc) {
        split_pad<false><<<(pr * pc + 255) / 256, 256, 0, stream>>>(W, Wh, Wl, r, c, pr, pc);
    };
    auto spp = [&](const float* W, short* Wh, short* Wl) {  // LSTM gate-permuted
        split_pad<true><<<(512 * 128 + 255) / 256, 256, 0, stream>>>(W, Wh, Wl, 512, 128, 512, 128);
    };
    sp(LC_W1, W1hL, W1lL, 400, 128, 512, 128);
    sp(CL_W1, W1hC, W1lC, 400, 128, 512, 128);
    sp(LC_W2, W2hL, W2lL, 200, 400, 256, 416);
    sp(CL_W2, W2hC, W2lC, 200, 400, 256, 416);
    sp(LC_W3, W3hL, W3lL, 128, 200, 128, 224);
    sp(CL_W3, W3hC, W3lC, 128, 200, 128, 224);
    spp(L_Wih, WihhL, WihlL);
    spp(L_Whh, WhhhL, WhhlL);
    spp(C_Wih, WihhC, WihlC);
    spp(C_Whh, WhhhC, WhhlC);
    sp(V_W1, V1h, V1l, 400, 128, 512, 128);
    sp(V_W2, V2h, V2l, 200, 400, 256, 416);

    const int nelem_blocks = (int)((NE + 255) / 256);
    init_states<<<nelem_blocks, 256, 0, stream>>>(L_init, C_init, HAh, HAl, CA, accum);

    // --- 30 message-passing steps (5 kernels each) ---
    short *Hch = HAh, *Hcl = HAl, *Hnh = HBh, *Hnl = HBl;
    float *Ccur = CA, *Cnxt = CB;
    for (int step = 0; step < TSTEPS; ++step) {
        mfma_gemm<128, 128, 128, 1, false, true><<<dim3(4, 96), 256, 0, stream>>>(
            Hch, Hcl, nullptr, nullptr,
            W1hL, W1lL, W1hC, W1lC, nullptr, nullptr, nullptr, nullptr,
            LC_b1, CL_b1, H1h, H1l, nullptr, nullptr, nullptr, 400, 416);
        mfma_gemm<128, 128, 416, 1, false, true><<<dim3(2, 96), 256, 0, stream>>>(
            H1h, H1l, nullptr, nullptr,
            W2hL, W2lL, W2hC, W2lC, nullptr, nullptr, nullptr, nullptr,
            LC_b2, CL_b2, H2h, H2l, nullptr, nullptr, nullptr, 200, 224);
        mfma_gemm<64, 128, 224, 0, false, false><<<dim3(1, 192), 128, 0, stream>>>(
            H2h, H2l, nullptr, nullptr,
            W3hL, W3lL, W3hC, W3lC, nullptr, nullptr, nullptr, nullptr,
            LC_b3, CL_b3, nullptr, nullptr, X, nullptr, nullptr, 128, 128);
        spmm_kernel<<<(NRREAL + 3) / 4, 256, 0, stream>>>(Lp, Lidx, Tp, Tidx, X, msgsH, msgsL);
        mfma_gemm<128, 128, 128, 3, true, false><<<dim3(4, 96), 256, 0, stream>>>(
            msgsH, msgsL, Hch, Hcl,
            WihhL, WihlL, WihhC, WihlC, WhhhL, WhhlL, WhhhC, WhhlC,
            L_b, C_b, Hnh, Hnl, nullptr, Ccur, Cnxt, 512, 512);
        short* th = Hch; Hch = Hnh; Hnh = th;
        short* tl = Hcl; Hcl = Hnl; Hnl = tl;
        float* tc = Ccur; Ccur = Cnxt; Cnxt = tc;
    }

    // --- vote MLP + logit (lit rows only: 32 row tiles of 128) ---
    mfma_gemm<128, 128, 128, 1, false, true><<<dim3(4, 32), 256, 0, stream>>>(
        Hch, Hcl, nullptr, nullptr,
        V1h, V1l, V1h, V1l, nullptr, nullptr, nullptr, nullptr,
        V_b1, V_b1, H1h, H1l, nullptr, nullptr, nullptr, 400, 416);
    mfma_gemm<128, 128, 416, 1, false, true><<<dim3(2, 32), 256, 0, stream>>>(
        H1h, H1l, nullptr, nullptr,
        V2h, V2l, V2h, V2l, nullptr, nullptr, nullptr, nullptr,
        V_b2, V_b2, H2h, H2l, nullptr, nullptr, nullptr, 200, 224);
    vote_reduce<<<(NL + 3) / 4, 256, 0, stream>>>(H2h, H2l, V_W3, V_b3, accum);
    finalize_logit<<<1, 1, 0, stream>>>(accum, out);
}

// Round 7
// 4360.007 us; speedup vs baseline: 1.3180x; 1.0114x over previous
//
#include <hip/hip_runtime.h>

#define NL 4000
#define NC 8000
#define EMB 128
#define ROWC0 4096           // clause region start
#define NRP 12288            // padded total rows
#define NRREAL (ROWC0 + NC)  // 12096 rows with data
#define TSTEPS 30
#define LCHUNK 80
#define NCHUNK 50

typedef __attribute__((ext_vector_type(8))) short bf16x8;
typedef __attribute__((ext_vector_type(4))) float f32x4;

__device__ __forceinline__ short f2bf(float x) {
    union { float f; unsigned u; } v; v.f = x;
    unsigned r = v.u + 0x7fffu + ((v.u >> 16) & 1u);
    return (short)(r >> 16);
}
__device__ __forceinline__ float bf2f(short s) {
    union { unsigned u; float f; } v; v.u = ((unsigned)(unsigned short)s) << 16;
    return v.f;
}
__device__ __forceinline__ float sigf(float x) { return 1.f / (1.f + expf(-x)); }
__device__ __forceinline__ float2 h2f2(unsigned u) {
    union { unsigned v; _Float16 h[2]; } x; x.v = u;
    return make_float2((float)x.h[0], (float)x.h[1]);
}

__device__ __forceinline__ void gload16(const void* g, void* l) {
    __builtin_amdgcn_global_load_lds(
        (const __attribute__((address_space(1))) unsigned int*)g,
        (__attribute__((address_space(3))) unsigned int*)l, 16, 0, 0);
}

// ---------------------------------------------------------------------------
// Split-bf16 MFMA GEMM, 2-stage pipelined double-buffered K-loop (R3/R6
// verified). product = Ah*Wh + Ah*Wl + Al*Wh in fp32 acc.
// OUTM: 0 = fp32 out, 1 = split-bf16 out (+relu), 4 = fp16 out,
//       3 = fused LSTM epilogue (gate-permuted weights, R5/R6-verified).
// Rows < ROWC0 use the L weight set, else the C set.
// ---------------------------------------------------------------------------
template<int BM_, int BN_, int KS, int OUTM, bool TWOA, bool RELU>
__global__ __launch_bounds__((BM_/64)*(BN_/64)*64) void mfma_gemm(
    const short* __restrict__ A1h, const short* __restrict__ A1l,
    const short* __restrict__ A2h, const short* __restrict__ A2l,
    const short* __restrict__ B1hL, const short* __restrict__ B1lL,
    const short* __restrict__ B1hC, const short* __restrict__ B1lC,
    const short* __restrict__ B2hL, const short* __restrict__ B2lL,
    const short* __restrict__ B2hC, const short* __restrict__ B2lC,
    const float* __restrict__ biasL, const float* __restrict__ biasC,
    short* __restrict__ OH, short* __restrict__ OL, float* __restrict__ OF,
    const float* __restrict__ Cold, float* __restrict__ Cnew,
    int Freal, int Fstore)
{
    constexpr int T = (BM_/64)*(BN_/64)*64;
    constexpr int KIT = KS / 32;
    constexpr int NIT = (TWOA ? 2 : 1) * KIT;

    __shared__ short sAh[2][BM_*32];
    __shared__ short sAl[2][BM_*32];
    __shared__ short sBh[2][BN_*32];
    __shared__ short sBl[2][BN_*32];

    const int row0 = blockIdx.y * BM_;
    const int c0 = blockIdx.x * BN_;
    const bool isC = (row0 >= ROWC0);
    const int t = threadIdx.x;
    const int lane = t & 63;
    const int w = t >> 6;
    constexpr int WCn = BN_/64;
    const int wr = w / WCn, wc = w % WCn;
    const int l15 = lane & 15;

    f32x4 acc[4][4] = {};

    auto stage = [&](int buf, int it) {
        const int ph = it / KIT;
        const int kc = (it - ph * KIT) * 32;
        const short *Ah, *Al, *Bh, *Bl;
        if (TWOA && ph) {
            Ah = A2h; Al = A2l;
            Bh = isC ? B2hC : B2hL; Bl = isC ? B2lC : B2lL;
        } else {
            Ah = A1h; Al = A1l;
            Bh = isC ? B1hC : B1hL; Bl = isC ? B1lC : B1lL;
        }
#pragma unroll
        for (int q = 0; q < BM_*4/T; ++q) {
            int c = q * T + t;
            int row = c >> 2, slot = c & 3;
            int gk = kc + ((slot ^ ((row >> 1) & 3)) << 3);
            size_t gi = (size_t)(row0 + row) * KS + gk;
            gload16(Ah + gi, &sAh[buf][c * 8]);
            gload16(Al + gi, &sAl[buf][c * 8]);
        }
#pragma unroll
        for (int q = 0; q < BN_*4/T; ++q) {
            int c = q * T + t;
            int row = c >> 2, slot = c & 3;
            int gk = kc + ((slot ^ ((row >> 1) & 3)) << 3);
            size_t gi = (size_t)(c0 + row) * KS + gk;
            gload16(Bh + gi, &sBh[buf][c * 8]);
            gload16(Bl + gi, &sBl[buf][c * 8]);
        }
    };

    // prologue
    stage(0, 0);
    asm volatile("s_waitcnt vmcnt(0)" ::: "memory");
    __syncthreads();

    int cur = 0;
    for (int it = 0; it < NIT; ++it) {
        if (it + 1 < NIT) stage(cur ^ 1, it + 1);   // loads fly under MFMAs

        bf16x8 af[4][2], bfr[4][2];
#pragma unroll
        for (int s = 0; s < 4; ++s) {
            int row = wr * 64 + s * 16 + l15;
            int slot = (lane >> 4) ^ ((row >> 1) & 3);
            int idx = row * 32 + slot * 8;
            af[s][0] = *(const bf16x8*)&sAh[cur][idx];
            af[s][1] = *(const bf16x8*)&sAl[cur][idx];
            int colr = wc * 64 + s * 16 + l15;
            int slotb = (lane >> 4) ^ ((colr >> 1) & 3);
            int idxb = colr * 32 + slotb * 8;
            bfr[s][0] = *(const bf16x8*)&sBh[cur][idxb];
            bfr[s][1] = *(const bf16x8*)&sBl[cur][idxb];
        }
#pragma unroll
        for (int s = 0; s < 4; ++s)
#pragma unroll
            for (int u = 0; u < 4; ++u) {
                acc[s][u] = __builtin_amdgcn_mfma_f32_16x16x32_bf16(af[s][0], bfr[u][0], acc[s][u], 0, 0, 0);
                acc[s][u] = __builtin_amdgcn_mfma_f32_16x16x32_bf16(af[s][0], bfr[u][1], acc[s][u], 0, 0, 0);
                acc[s][u] = __builtin_amdgcn_mfma_f32_16x16x32_bf16(af[s][1], bfr[u][0], acc[s][u], 0, 0, 0);
            }

        if (it + 1 < NIT) {
            asm volatile("s_waitcnt vmcnt(0)" ::: "memory");
            __syncthreads();
            cur ^= 1;
        }
    }

    if (OUTM != 3) {
        // C/D frag layout: col = lane&15, row = (lane>>4)*4 + reg (m89)
#pragma unroll
        for (int u = 0; u < 4; ++u) {
            int col = c0 + wc * 64 + u * 16 + l15;
            if (col >= Fstore) continue;
            float bv = (col < Freal) ? (isC ? biasC[col] : biasL[col]) : 0.f;
#pragma unroll
            for (int s = 0; s < 4; ++s) {
#pragma unroll
                for (int j = 0; j < 4; ++j) {
                    int row = row0 + wr * 64 + s * 16 + (lane >> 4) * 4 + j;
                    float v = acc[s][u][j] + bv;
                    if (RELU) v = fmaxf(v, 0.f);
                    size_t oi = (size_t)row * Fstore + col;
                    if (OUTM == 1) {
                        short h = f2bf(v);
                        OH[oi] = h;
                        OL[oi] = f2bf(v - bf2f(h));
                    } else if (OUTM == 4) {
                        ((_Float16*)OF)[oi] = (_Float16)v;
                    } else {
                        OF[oi] = v;
                    }
                }
            }
        }
    } else {
        // Fused LSTM epilogue (R5/R6-verified). colp = permuted gate col 4j+g.
        const int q = lane & 3;
#pragma unroll
        for (int u = 0; u < 4; ++u) {
            int colp = c0 + wc * 64 + u * 16 + l15;
            int wrr = (colp & 3) * 128 + (colp >> 2);   // original gate row (bias)
            float bv = isC ? biasC[wrr] : biasL[wrr];
            int j = colp >> 2;
#pragma unroll
            for (int s = 0; s < 4; ++s) {
                float ii = 0.f, ff = 0.f, gg = 0.f, oo = 0.f;
#pragma unroll
                for (int r2 = 0; r2 < 4; ++r2) {
                    float v0 = acc[s][u][r2] + bv;
                    float x1 = __shfl_xor(v0, 1);
                    float x2 = __shfl_xor(v0, 2);
                    float x3 = __shfl_xor(v0, 3);
                    float iv = (q == 0) ? v0 : (q == 1) ? x1 : (q == 2) ? x2 : x3;
                    float fv = (q == 0) ? x1 : (q == 1) ? v0 : (q == 2) ? x3 : x2;
                    float gv = (q == 0) ? x2 : (q == 1) ? x3 : (q == 2) ? v0 : x1;
                    float ov = (q == 0) ? x3 : (q == 1) ? x2 : (q == 2) ? x1 : v0;
                    if (q == r2) { ii = iv; ff = fv; gg = gv; oo = ov; }
                }
                int row = row0 + wr * 64 + s * 16 + (lane >> 4) * 4 + q;
                size_t ci = (size_t)row * 128 + j;
                float c2 = sigf(ff) * Cold[ci] + sigf(ii) * tanhf(gg);
                float h2 = sigf(oo) * tanhf(c2);
                Cnew[ci] = c2;
                short h = f2bf(h2);
                OH[ci] = h;
                OL[ci] = f2bf(h2 - bf2f(h));
            }
        }
    }
}

// ---------------------------------------------------------------------------
// Weight prep: zero-padded split into hi/lo bf16. PERM=true applies the
// LSTM gate permutation: output row p holds input row ((p&3)<<7)|(p>>2).
// ---------------------------------------------------------------------------
template<bool PERM>
__global__ __launch_bounds__(256) void split_pad(
    const float* __restrict__ W, short* __restrict__ Wh, short* __restrict__ Wl,
    int rows, int cols, int prows, int pcols)
{
    int i = blockIdx.x * 256 + threadIdx.x;
    if (i >= prows * pcols) return;
    int p = i / pcols, c = i - p * pcols;
    int r = PERM ? (((p & 3) << 7) | (p >> 2)) : p;
    float v = (r < rows && c < cols) ? W[(size_t)r * cols + c] : 0.f;
    short h = f2bf(v);
    Wh[i] = h;
    Wl[i] = f2bf(v - bf2f(h));
}

// ---------------------------------------------------------------------------
// SpMM gather: fp16 X in (half the traffic of fp32; half-ulp 2^-12 -> ~8x
// finer than R4's failed bf16), fp32 acc, split-bf16 msgs out.
// 4 rows/block, 64 threads/row, 2 cols (one dword) per thread.
// ---------------------------------------------------------------------------
__global__ __launch_bounds__(256) void spmm_kernel(
    const int* __restrict__ Lp, const int* __restrict__ Li,
    const int* __restrict__ Tp, const int* __restrict__ Ti,
    const _Float16* __restrict__ X, short* __restrict__ mh, short* __restrict__ ml)
{
    const int r = blockIdx.x * 4 + (threadIdx.x >> 6);
    const int cp = (threadIdx.x & 63) * 2;
    if (r >= NRREAL) return;
    float s0 = 0.f, s1 = 0.f;
    if (r < NL) {
        int b = Lp[r], e = Lp[r + 1];
        int i = b;
        for (; i + 3 < e; i += 4) {
            unsigned u0 = *(const unsigned*)&X[(size_t)(ROWC0 + Li[i]) * EMB + cp];
            unsigned u1 = *(const unsigned*)&X[(size_t)(ROWC0 + Li[i + 1]) * EMB + cp];
            unsigned u2 = *(const unsigned*)&X[(size_t)(ROWC0 + Li[i + 2]) * EMB + cp];
            unsigned u3 = *(const unsigned*)&X[(size_t)(ROWC0 + Li[i + 3]) * EMB + cp];
            float2 v0 = h2f2(u0), v1 = h2f2(u1), v2 = h2f2(u2), v3 = h2f2(u3);
            s0 += v0.x + v1.x + v2.x + v3.x;
            s1 += v0.y + v1.y + v2.y + v3.y;
        }
        for (; i < e; ++i) {
            float2 v = h2f2(*(const unsigned*)&X[(size_t)(ROWC0 + Li[i]) * EMB + cp]);
            s0 += v.x; s1 += v.y;
        }
    } else if (r >= ROWC0) {
        int c = r - ROWC0;
        int b = Tp[c], e = Tp[c + 1];
        int i = b;
        for (; i + 3 < e; i += 4) {
            unsigned u0 = *(const unsigned*)&X[(size_t)Ti[i] * EMB + cp];
            unsigned u1 = *(const unsigned*)&X[(size_t)Ti[i + 1] * EMB + cp];
            unsigned u2 = *(const unsigned*)&X[(size_t)Ti[i + 2] * EMB + cp];
            unsigned u3 = *(const unsigned*)&X[(size_t)Ti[i + 3] * EMB + cp];
            float2 v0 = h2f2(u0), v1 = h2f2(u1), v2 = h2f2(u2), v3 = h2f2(u3);
            s0 += v0.x + v1.x + v2.x + v3.x;
            s1 += v0.y + v1.y + v2.y + v3.y;
        }
        for (; i < e; ++i) {
            float2 v = h2f2(*(const unsigned*)&X[(size_t)Ti[i] * EMB + cp]);
            s0 += v.x; s1 += v.y;
        }
    }
    size_t oi = (size_t)r * EMB + cp;
    short h0 = f2bf(s0), h1 = f2bf(s1);
    *(unsigned*)&mh[oi] = (unsigned)(unsigned short)h0 | ((unsigned)(unsigned short)h1 << 16);
    short l0 = f2bf(s0 - bf2f(h0)), l1 = f2bf(s1 - bf2f(h1));
    *(unsigned*)&ml[oi] = (unsigned)(unsigned short)l0 | ((unsigned)(unsigned short)l1 << 16);
}

__global__ __launch_bounds__(256) void init_states(
    const float* __restrict__ Li, const float* __restrict__ Ci,
    short* __restrict__ Hh, short* __restrict__ Hl, float* __restrict__ C,
    float* __restrict__ accum)
{
    size_t idx = (size_t)blockIdx.x * 256 + threadIdx.x;
    if (idx >= (size_t)NRP * EMB) return;
    int r = (int)(idx >> 7);
    int e = (int)(idx & 127);
    float h = 0.f;
    if (r < NL) h = Li[e];
    else if (r >= ROWC0 && r < NRREAL) h = Ci[e];
    short hh = f2bf(h);
    Hh[idx] = hh;
    Hl[idx] = f2bf(h - bf2f(hh));
    C[idx] = 0.f;
    if (idx == 0) accum[0] = 0.f;
}

// ---------------------------------------------------------------------------
// CSR build (verified rounds 1-6)
// ---------------------------------------------------------------------------
__global__ __launch_bounds__(256) void count_rows_L(const float* __restrict__ M, int* __restrict__ cnt)
{
    int l = blockIdx.x, t = threadIdx.x;
    int c_ = 0;
    for (int c = t; c < NC; c += 256) c_ += (M[(size_t)l * NC + c] != 0.f) ? 1 : 0;
#pragma unroll
    for (int off = 32; off > 0; off >>= 1) c_ += __shfl_down(c_, off);
    __shared__ int w[4];
    if ((t & 63) == 0) w[t >> 6] = c_;
    __syncthreads();
    if (t == 0) cnt[l] = w[0] + w[1] + w[2] + w[3];
}

__global__ __launch_bounds__(256) void scan_excl(const int* __restrict__ in, int* __restrict__ out, int n)
{
    const int t = threadIdx.x;
    const int per = (n + 255) >> 8;
    __shared__ int part[256];
    int s = 0;
    const int start = t * per;
    for (int i = 0; i < per; ++i) { int idx = start + i; if (idx < n) s += in[idx]; }
    part[t] = s;
    __syncthreads();
    for (int off = 1; off < 256; off <<= 1) {
        int v = (t >= off) ? part[t - off] : 0;
        __syncthreads();
        part[t] += v;
        __syncthreads();
    }
    int run = (t == 0) ? 0 : part[t - 1];
    for (int i = 0; i < per; ++i) {
        int idx = start + i;
        if (idx < n) { out[idx] = run; run += in[idx]; }
    }
    if (t == 255) out[n] = part[255];
}

__global__ __launch_bounds__(256) void fill_L(const float* __restrict__ M,
                                              const int* __restrict__ Lp, int* __restrict__ Lidx)
{
    int l = blockIdx.x, t = threadIdx.x, lane = t & 63, wid = t >> 6;
    __shared__ int wcnt[4];
    __shared__ int base;
    if (t == 0) base = Lp[l];
    __syncthreads();
    for (int c0 = 0; c0 < NC; c0 += 256) {
        int c = c0 + t;
        bool p = (c < NC) && (M[(size_t)l * NC + c] != 0.f);
        unsigned long long m = __ballot(p);
        if (lane == 0) wcnt[wid] = (int)__popcll(m);
        __syncthreads();
        int off = base;
        for (int w = 0; w < wid; ++w) off += wcnt[w];
        int rank = (int)__popcll(m & ((1ull << lane) - 1ull));
        if (p) Lidx[off + rank] = c;
        __syncthreads();
        if (t == 0) base += wcnt[0] + wcnt[1] + wcnt[2] + wcnt[3];
        __syncthreads();
    }
}

__global__ __launch_bounds__(256) void count_T(const float* __restrict__ M, int* __restrict__ cnt2d)
{
    int s = blockIdx.y;
    int c = blockIdx.x * 256 + threadIdx.x;
    if (c >= NC) return;
    int n = 0;
    int l0 = s * LCHUNK, l1 = l0 + LCHUNK;
    for (int l = l0; l < l1; ++l) n += (M[(size_t)l * NC + c] != 0.f) ? 1 : 0;
    cnt2d[(size_t)s * NC + c] = n;
}

__global__ __launch_bounds__(256) void colscan_T(const int* __restrict__ cnt2d,
                                                 int* __restrict__ cum2d, int* __restrict__ cntT)
{
    int c = blockIdx.x * 256 + threadIdx.x;
    if (c >= NC) return;
    int run = 0;
    for (int s = 0; s < NCHUNK; ++s) {
        cum2d[(size_t)s * NC + c] = run;
        run += cnt2d[(size_t)s * NC + c];
    }
    cntT[c] = run;
}

__global__ __launch_bounds__(256) void fill_T(const float* __restrict__ M,
                                              const int* __restrict__ Tp, const int* __restrict__ cum2d,
                                              int* __restrict__ Tidx)
{
    int s = blockIdx.y;
    int c = blockIdx.x * 256 + threadIdx.x;
    if (c >= NC) return;
    int pos = Tp[c] + cum2d[(size_t)s * NC + c];
    int l0 = s * LCHUNK, l1 = l0 + LCHUNK;
    for (int l = l0; l < l1; ++l) {
        if (M[(size_t)l * NC + c] != 0.f) Tidx[pos++] = l;
    }
}

// ---------------------------------------------------------------------------
// Vote epilogue
// ---------------------------------------------------------------------------
__global__ __launch_bounds__(256) void vote_reduce(
    const short* __restrict__ H2h, const short* __restrict__ H2l,
    const float* __restrict__ W3, const float* __restrict__ b3, float* __restrict__ accum)
{
    int wid = threadIdx.x >> 6, lane = threadIdx.x & 63;
    int r = blockIdx.x * 4 + wid;
    float s = 0.f;
    if (r < NL) {
        const short* xh = &H2h[(size_t)r * 224];
        const short* xl = &H2l[(size_t)r * 224];
        for (int k = lane; k < 200; k += 64) s += (bf2f(xh[k]) + bf2f(xl[k])) * W3[k];
    }
#pragma unroll
    for (int off = 32; off > 0; off >>= 1) s += __shfl_down(s, off);
    if (lane == 0 && r < NL) {
        float v = 1.f / (1.f + expf(-(s + b3[0])));
        atomicAdd(accum, v);
    }
}

__global__ void finalize_logit(const float* __restrict__ accum, float* __restrict__ out)
{
    float avg = accum[0] / (float)NL;
    out[0] = logf(avg / (1.f - avg));
}

// ---------------------------------------------------------------------------
// Host launcher
// ---------------------------------------------------------------------------
extern "C" void kernel_launch(void* const* d_in, const int* in_sizes, int n_in,
                              void* d_out, int out_size, void* d_ws, size_t ws_size,
                              hipStream_t stream)
{
    const float* M      = (const float*)d_in[0];
    const float* L_init = (const float*)d_in[1];
    const float* C_init = (const float*)d_in[2];
    const float* LC_W1 = (const float*)d_in[3];  const float* LC_b1 = (const float*)d_in[4];
    const float* LC_W2 = (const float*)d_in[5];  const float* LC_b2 = (const float*)d_in[6];
    const float* LC_W3 = (const float*)d_in[7];  const float* LC_b3 = (const float*)d_in[8];
    const float* CL_W1 = (const float*)d_in[9];  const float* CL_b1 = (const float*)d_in[10];
    const float* CL_W2 = (const float*)d_in[11]; const float* CL_b2 = (const float*)d_in[12];
    const float* CL_W3 = (const float*)d_in[13]; const float* CL_b3 = (const float*)d_in[14];
    const float* L_Wih = (const float*)d_in[15]; const float* L_Whh = (const float*)d_in[16];
    const float* L_b   = (const float*)d_in[17];
    const float* C_Wih = (const float*)d_in[18]; const float* C_Whh = (const float*)d_in[19];
    const float* C_b   = (const float*)d_in[20];
    const float* V_W1 = (const float*)d_in[21]; const float* V_b1 = (const float*)d_in[22];
    const float* V_W2 = (const float*)d_in[23]; const float* V_b2 = (const float*)d_in[24];
    const float* V_W3 = (const float*)d_in[25]; const float* V_b3 = (const float*)d_in[26];
    float* out = (float*)d_out;

    char* ws = (char*)d_ws;
    size_t off = 0;
    auto alloc = [&](size_t bytes) -> void* {
        void* p = ws + off;
        off += (bytes + 255) & ~(size_t)255;
        return p;
    };
    const size_t NE = (size_t)NRP * EMB;
    short* HAh = (short*)alloc(NE * 2); short* HAl = (short*)alloc(NE * 2);
    short* HBh = (short*)alloc(NE * 2); short* HBl = (short*)alloc(NE * 2);
    float* CA = (float*)alloc(NE * 4);  float* CB = (float*)alloc(NE * 4);
    short* msgsH = (short*)alloc(NE * 2); short* msgsL = (short*)alloc(NE * 2);
    _Float16* X = (_Float16*)alloc(NE * 2);
    short* H1h = (short*)alloc((size_t)NRP * 416 * 2); short* H1l = (short*)alloc((size_t)NRP * 416 * 2);
    short* H2h = (short*)alloc((size_t)NRP * 224 * 2); short* H2l = (short*)alloc((size_t)NRP * 224 * 2);
    float* accum = (float*)alloc(256);
    // split/padded weights (B-tile rows padded to 128-multiples)
    short* W1hL = (short*)alloc(512 * 128 * 2); short* W1lL = (short*)alloc(512 * 128 * 2);
    short* W1hC = (short*)alloc(512 * 128 * 2); short* W1lC = (short*)alloc(512 * 128 * 2);
    short* W2hL = (short*)alloc(256 * 416 * 2); short* W2lL = (short*)alloc(256 * 416 * 2);
    short* W2hC = (short*)alloc(256 * 416 * 2); short* W2lC = (short*)alloc(256 * 416 * 2);
    short* W3hL = (short*)alloc(128 * 224 * 2); short* W3lL = (short*)alloc(128 * 224 * 2);
    short* W3hC = (short*)alloc(128 * 224 * 2); short* W3lC = (short*)alloc(128 * 224 * 2);
    short* WihhL = (short*)alloc(512 * 128 * 2); short* WihlL = (short*)alloc(512 * 128 * 2);
    short* WhhhL = (short*)alloc(512 * 128 * 2); short* WhhlL = (short*)alloc(512 * 128 * 2);
    short* WihhC = (short*)alloc(512 * 128 * 2); short* WihlC = (short*)alloc(512 * 128 * 2);
    short* WhhhC = (short*)alloc(512 * 128 * 2); short* WhhlC = (short*)alloc(512 * 128 * 2);
    short* V1h = (short*)alloc(512 * 128 * 2); short* V1l = (short*)alloc(512 * 128 * 2);
    short* V2h = (short*)alloc(256 * 416 * 2); short* V2l = (short*)alloc(256 * 416 * 2);
    // CSR
    int* Lp   = (int*)alloc(4104 * 4);
    int* Tp   = (int*)alloc(8104 * 4);
    int* Lidx = (int*)alloc(1000000 * 4);
    int* Tidx = (int*)alloc(1000000 * 4);
    int* cnt2d = (int*)alloc((size_t)NCHUNK * NC * 4);
    int* cum2d = (int*)alloc((size_t)NCHUNK * NC * 4);
    int* cntL = (int*)alloc(4096 * 4);
    int* cntT = (int*)alloc(8192 * 4);
    (void)ws_size; (void)in_sizes; (void)n_in; (void)out_size;

    // --- CSR build ---
    count_rows_L<<<NL, 256, 0, stream>>>(M, cntL);
    scan_excl<<<1, 256, 0, stream>>>(cntL, Lp, NL);
    fill_L<<<NL, 256, 0, stream>>>(M, Lp, Lidx);
    {
        dim3 g((NC + 255) / 256, NCHUNK);
        count_T<<<g, 256, 0, stream>>>(M, cnt2d);
        colscan_T<<<(NC + 255) / 256, 256, 0, stream>>>(cnt2d, cum2d, cntT);
        scan_excl<<<1, 256, 0, stream>>>(cntT, Tp, NC);
        fill_T<<<g, 256, 0, stream>>>(M, Tp, cum2d, Tidx);
    }

    // --- weight split/pad ---
    auto sp = [&](const float* W, short* Wh, short* Wl, int r, int c, int pr, int pc) {
        split_pad<false><<<(pr * pc + 255) / 256, 256, 0, stream>>>(W, Wh, Wl, r, c, pr, pc);
    };
    auto spp = [&](const float* W, short* Wh, short* Wl) {  // LSTM gate-permuted
        split_pad<true><<<(512 * 128 + 255) / 256, 256, 0, stream>>>(W, Wh, Wl, 512, 128, 512, 128);
    };
    sp(LC_W1, W1hL, W1lL, 400, 128, 512, 128);
    sp(CL_W1, W1hC, W1lC, 400, 128, 512, 128);
    sp(LC_W2, W2hL, W2lL, 200, 400, 256, 416);
    sp(CL_W2, W2hC, W2lC, 200, 400, 256, 416);
    sp(LC_W3, W3hL, W3lL, 128, 200, 128, 224);
    sp(CL_W3, W3hC, W3lC, 128, 200, 128, 224);
    spp(L_Wih, WihhL, WihlL);
    spp(L_Whh, WhhhL, WhhlL);
    spp(C_Wih, WihhC, WihlC);
    spp(C_Whh, WhhhC, WhhlC);
    sp(V_W1, V1h, V1l, 400, 128, 512, 128);
    sp(V_W2, V2h, V2l, 200, 400, 256, 416);

    const int nelem_blocks = (int)((NE + 255) / 256);
    init_states<<<nelem_blocks, 256, 0, stream>>>(L_init, C_init, HAh, HAl, CA, accum);

    // --- 30 message-passing steps (5 kernels each, BM=64 for CU coverage) ---
    short *Hch = HAh, *Hcl = HAl, *Hnh = HBh, *Hnl = HBl;
    float *Ccur = CA, *Cnxt = CB;
    for (int step = 0; step < TSTEPS; ++step) {
        mfma_gemm<64, 128, 128, 1, false, true><<<dim3(4, 192), 128, 0, stream>>>(
            Hch, Hcl, nullptr, nullptr,
            W1hL, W1lL, W1hC, W1lC, nullptr, nullptr, nullptr, nullptr,
            LC_b1, CL_b1, H1h, H1l, nullptr, nullptr, nullptr, 400, 416);
        mfma_gemm<64, 128, 416, 1, false, true><<<dim3(2, 192), 128, 0, stream>>>(
            H1h, H1l, nullptr, nullptr,
            W2hL, W2lL, W2hC, W2lC, nullptr, nullptr, nullptr, nullptr,
            LC_b2, CL_b2, H2h, H2l, nullptr, nullptr, nullptr, 200, 224);
        mfma_gemm<64, 128, 224, 4, false, false><<<dim3(1, 192), 128, 0, stream>>>(
            H2h, H2l, nullptr, nullptr,
            W3hL, W3lL, W3hC, W3lC, nullptr, nullptr, nullptr, nullptr,
            LC_b3, CL_b3, nullptr, nullptr, (float*)X, nullptr, nullptr, 128, 128);
        spmm_kernel<<<(NRREAL + 3) / 4, 256, 0, stream>>>(Lp, Lidx, Tp, Tidx, X, msgsH, msgsL);
        mfma_gemm<64, 128, 128, 3, true, false><<<dim3(4, 192), 128, 0, stream>>>(
            msgsH, msgsL, Hch, Hcl,
            WihhL, WihlL, WihhC, WihlC, WhhhL, WhhlL, WhhhC, WhhlC,
            L_b, C_b, Hnh, Hnl, nullptr, Ccur, Cnxt, 512, 512);
        short* th = Hch; Hch = Hnh; Hnh = th;
        short* tl = Hcl; Hcl = Hnl; Hnl = tl;
        float* tc = Ccur; Ccur = Cnxt; Cnxt = tc;
    }

    // --- vote MLP + logit (lit rows only: 32 row tiles of 128) ---
    mfma_gemm<128, 128, 128, 1, false, true><<<dim3(4, 32), 256, 0, stream>>>(
        Hch, Hcl, nullptr, nullptr,
        V1h, V1l, V1h, V1l, nullptr, nullptr, nullptr, nullptr,
        V_b1, V_b1, H1h, H1l, nullptr, nullptr, nullptr, 400, 416);
    mfma_gemm<128, 128, 416, 1, false, true><<<dim3(2, 32), 256, 0, stream>>>(
        H1h, H1l, nullptr, nullptr,
        V2h, V2l, V2h, V2l, nullptr, nullptr, nullptr, nullptr,
        V_b2, V_b2, H2h, H2l, nullptr, nullptr, nullptr, 200, 224);
    vote_reduce<<<(NL + 3) / 4, 256, 0, stream>>>(H2h, H2l, V_W3, V_b3, accum);
    finalize_logit<<<1, 1, 0, stream>>>(accum, out);
}